// Round 23
// baseline (97.383 us; speedup 1.0000x reference)
//
#include <hip/hip_runtime.h>
#include <math.h>

#define T_TOK 32768      // B*N = 2*16384
#define DIM 128
#define NHEADS 4
#define HD 32
#define NEXP 16
#define EHID 256
#define NWIN 512
#define EPS 1e-5f
#define CPAD 16          // counter padding: 64B apart
#define XFS 133          // xf stride (133%32=5 -> 2-way max on fp32 accesses)

typedef _Float16 f16x8 __attribute__((ext_vector_type(8)));
typedef _Float16 f16x4 __attribute__((ext_vector_type(4)));
typedef float f32x4v __attribute__((ext_vector_type(4)));

#define MFMA16(a, b, c) __builtin_amdgcn_mfma_f32_16x16x32_f16(a, b, c, 0, 0, 0)
#define LO_SCALE 4096.0f
#define LO_INV (1.0f / 4096.0f)

// swizzled f16 index into a [R][128] tile (16B chunks XOR'd by row&7)
__device__ __forceinline__ int sw128(int r, int c) {
    return r * 128 + (((c >> 3) ^ (r & 7)) << 3) + (c & 7);
}
// swizzled f16 index into a [R][64] tile (V^T)
__device__ __forceinline__ int sw64(int r, int c) {
    return r * 64 + (((c >> 3) ^ (r & 7)) << 3) + (c & 7);
}
// P-tile swizzle: XOR = (row ^ row>>3)&7
__device__ __forceinline__ int sw64p(int r, int c) {
    return r * 64 + (((c >> 3) ^ ((r ^ (r >> 3)) & 7)) << 3) + (c & 7);
}
// swizzled f16 index into [64 tok][256 hid] tile
__device__ __forceinline__ int swht(int tok, int hid) {
    return tok * 256 + (((hid >> 3) ^ (tok & 7)) << 3) + (hid & 7);
}

// ---------------- qkv(hi)/proj(hi+lo) conversion + gate fold + counter zero ----------------
__global__ __launch_bounds__(256) void k_cvt(
    const float* __restrict__ wqkv, const float* __restrict__ wproj,
    const float* __restrict__ gw, const float* __restrict__ ln2_g,
    const float* __restrict__ ln2_b,
    _Float16* __restrict__ wq_h,
    _Float16* __restrict__ wp_h, _Float16* __restrict__ wp_l,
    float* __restrict__ gw2, float* __restrict__ SA,
    int* __restrict__ counts)
{
    int i = blockIdx.x * 256 + threadIdx.x;
    if (blockIdx.x == 0 && threadIdx.x < NEXP * CPAD) counts[threadIdx.x] = 0;
    if (i < 3 * DIM * DIM / 4) {
        float4 f = ((const float4*)wqkv)[i];
        f16x4 h;
        h[0] = (_Float16)f.x; h[1] = (_Float16)f.y; h[2] = (_Float16)f.z; h[3] = (_Float16)f.w;
        *(f16x4*)(wq_h + (size_t)i * 4) = h;
    }
    if (i < DIM * DIM / 4) {
        float4 f = ((const float4*)wproj)[i];
        float fv[4] = {f.x, f.y, f.z, f.w};
        f16x4 h, l;
        #pragma unroll
        for (int j = 0; j < 4; ++j) {
            _Float16 hh = (_Float16)fv[j];
            h[j] = hh;
            l[j] = (_Float16)((fv[j] - (float)hh) * LO_SCALE);
        }
        *(f16x4*)(wp_h + (size_t)i * 4) = h;
        *(f16x4*)(wp_l + (size_t)i * 4) = l;
    }
    if (i < NEXP * DIM) {
        int k = i & 127;
        gw2[i] = ln2_g[k] * gw[i];
    }
    if (blockIdx.x == 1 && threadIdx.x < 2 * NEXP) {
        int e = threadIdx.x >> 1;
        const float* gr = gw + e * DIM;
        float s = 0.f;
        if (threadIdx.x & 1) {
            for (int k = 0; k < DIM; ++k) s = fmaf(ln2_b[k], gr[k], s);
        } else {
            for (int k = 0; k < DIM; ++k) s = fmaf(ln2_g[k], gr[k], s);
        }
        SA[threadIdx.x] = s;   // SA[2e]=S_e, SA[2e+1]=A_e
    }
}

// ---------------- fused LN1 + attn + proj + residual + LN2 + gate + routing ----------------
// 1024 threads (16 waves), 64KB LDS. Plain-f16 activations; split-fp16 proj
// weights only. x loaded ONCE (kept in regs for residual).
// NOTE: no min-occupancy arg in launch_bounds (spills otherwise).
__global__ __launch_bounds__(1024) void k_attn(
    const float* __restrict__ x,
    const float* __restrict__ ln_g, const float* __restrict__ ln_b,
    const _Float16* __restrict__ wq_h, const float* __restrict__ b_qkv,
    const _Float16* __restrict__ wp_h, const _Float16* __restrict__ wp_l,
    const float* __restrict__ b_proj,
    const float* __restrict__ ln2_g, const float* __restrict__ ln2_b,
    const float* __restrict__ gw2, const float* __restrict__ SA,
    const float* __restrict__ w1, const float* __restrict__ w2,
    _Float16* __restrict__ w1h, _Float16* __restrict__ w2h,
    float* __restrict__ x2, _Float16* __restrict__ y2,
    float* __restrict__ wgt, int* __restrict__ perm, int* __restrict__ counts)
{
    __shared__ __align__(16) char smem[65536];
    _Float16* xoh = (_Float16*)(smem);            // LN out; later O (plain f16)
    _Float16* qh  = (_Float16*)(smem + 16384);    // Q; later P(h0),P(h1)
    _Float16* kh  = (_Float16*)(smem + 32768);    // K; later P(h2),P(h3)
    _Float16* vth = (_Float16*)(smem + 49152);    // V^T [d][tok]
    // post-proj aliases (qh/kh/vth dead after barrier 4)
    float* xf  = (float*)(smem + 16384);          // [64][133] fp32 (ends 50432)
    float* mrs = (float*)(smem + 50688);          // [64][2] m,rs
    float* lgs = (float*)(smem + 51712);          // [64][20] gate logits (ends 56832)

    int tid = threadIdx.x;
    int w = tid >> 6, lane = tid & 63;
    int l15 = lane & 15, lg = lane >> 4;
    int wid = blockIdx.x;
    int wb = wid >> 8, wrr = (wid >> 4) & 15, wcc = wid & 15;
    const int tokbase = wb * 16384 + wrr * 1024 + wcc * 8;
    const size_t base = (size_t)tokbase * DIM;

    // ---- prefetch QKV B-frags (hi only) + bias ----
    // wave w owns tile w; waves 0-7 also own tile 16+w  (24 tiles of 16 cols)
    f16x8 qbh[2][4];
    float qbias[2];
    #pragma unroll
    for (int tl = 0; tl < 2; ++tl) {
        if (tl == 1 && w >= 8) break;
        int o = ((tl == 0) ? w : 16 + w) * 16 + l15;
        qbias[tl] = b_qkv[o];
        #pragma unroll
        for (int ks = 0; ks < 4; ++ks)
            qbh[tl][ks] = *(const f16x8*)(wq_h + (size_t)o * DIM + ks * 32 + lg * 8);
    }

    // ---- LN1: 16 threads per token, 8 dims each; plain f16 out; keep x in regs ----
    float xorig[8];
    {
        int tt = tid >> 4, sub = tid & 15;
        const float* xr = x + base + (size_t)(tt >> 3) * 16384 + (size_t)(tt & 7) * DIM + sub * 8;
        float s = 0.f, sq = 0.f;
        #pragma unroll
        for (int j = 0; j < 2; ++j) {
            float4 t4 = *(const float4*)(xr + j * 4);
            xorig[4 * j] = t4.x; xorig[4 * j + 1] = t4.y;
            xorig[4 * j + 2] = t4.z; xorig[4 * j + 3] = t4.w;
            s += (t4.x + t4.y) + (t4.z + t4.w);
            sq = fmaf(t4.x, t4.x, fmaf(t4.y, t4.y, fmaf(t4.z, t4.z, fmaf(t4.w, t4.w, sq))));
        }
        s += __shfl_xor(s, 1); sq += __shfl_xor(sq, 1);
        s += __shfl_xor(s, 2); sq += __shfl_xor(sq, 2);
        s += __shfl_xor(s, 4); sq += __shfl_xor(sq, 4);
        s += __shfl_xor(s, 8); sq += __shfl_xor(sq, 8);
        float m = s * (1.f / DIM);
        float var = sq * (1.f / DIM) - m * m;
        float rs = rsqrtf(var + EPS);
        _Float16 hh[8];
        #pragma unroll
        for (int j = 0; j < 8; ++j) {
            int k = sub * 8 + j;
            hh[j] = (_Float16)((xorig[j] - m) * rs * ln_g[k] + ln_b[k]);
        }
        *(f16x8*)&xoh[sw128(tt, sub * 8)] = *(const f16x8*)&hh[0];
    }
    __syncthreads();   // (1)

    // ---- QKV GEMM: <=2 col-tiles per wave, plain f16, 4 acc chains ----
    #pragma unroll
    for (int tl = 0; tl < 2; ++tl) {
        if (tl == 1 && w >= 8) break;
        int o = ((tl == 0) ? w : 16 + w) * 16 + l15;
        f32x4v am[4];
        #pragma unroll
        for (int rt = 0; rt < 4; ++rt) am[rt] = 0.0f;
        #pragma unroll
        for (int rt = 0; rt < 4; ++rt) {
            #pragma unroll
            for (int ks = 0; ks < 4; ++ks) {
                f16x8 ah = *(const f16x8*)&xoh[sw128(rt * 16 + l15, ks * 32 + lg * 8)];
                am[rt] = MFMA16(ah, qbh[tl][ks], am[rt]);
            }
        }
        float bias = qbias[tl];
        if (o < 256) {
            #pragma unroll
            for (int rt = 0; rt < 4; ++rt) {
                #pragma unroll
                for (int r = 0; r < 4; ++r) {
                    int row = rt * 16 + lg * 4 + r;
                    _Float16 h = (_Float16)(am[rt][r] + bias);
                    if (o < 128) qh[sw128(row, o)] = h;
                    else         kh[sw128(row, o - 128)] = h;
                }
            }
        } else {
            int d = o - 256;
            #pragma unroll
            for (int rt = 0; rt < 4; ++rt) {
                f16x4 vh4;
                #pragma unroll
                for (int r = 0; r < 4; ++r)
                    vh4[r] = (_Float16)(am[rt][r] + bias);
                *(f16x4*)&vth[sw64(d, rt * 16 + lg * 4)] = vh4;
            }
        }
    }
    __syncthreads();   // (2)

    // ---- scores + softmax: wave w -> head w&3, row-group w>>2 ----
    const float scale = 0.17677669529663687f;  // 1/sqrt(32)
    int h = w & 3;
    int qo = h * HD, rg = w >> 2;
    float preg[4][4];
    {
        f16x8 kbh[4];
        #pragma unroll
        for (int ct = 0; ct < 4; ++ct)
            kbh[ct] = *(const f16x8*)&kh[sw128(ct * 16 + l15, qo + lg * 8)];
        f16x8 qah = *(const f16x8*)&qh[sw128(rg * 16 + l15, qo + lg * 8)];
        f32x4v sm[4];
        #pragma unroll
        for (int ct = 0; ct < 4; ++ct) {
            sm[ct] = 0.0f;
            sm[ct] = MFMA16(qah, kbh[ct], sm[ct]);
        }
        #pragma unroll
        for (int r = 0; r < 4; ++r) {
            float v0 = sm[0][r] * scale;
            float v1 = sm[1][r] * scale;
            float v2 = sm[2][r] * scale;
            float v3 = sm[3][r] * scale;
            float mx = fmaxf(fmaxf(v0, v1), fmaxf(v2, v3));
            mx = fmaxf(mx, __shfl_xor(mx, 1));
            mx = fmaxf(mx, __shfl_xor(mx, 2));
            mx = fmaxf(mx, __shfl_xor(mx, 4));
            mx = fmaxf(mx, __shfl_xor(mx, 8));
            float e0 = expf(v0 - mx), e1 = expf(v1 - mx), e2 = expf(v2 - mx), e3 = expf(v3 - mx);
            float ss = (e0 + e1) + (e2 + e3);
            ss += __shfl_xor(ss, 1); ss += __shfl_xor(ss, 2);
            ss += __shfl_xor(ss, 4); ss += __shfl_xor(ss, 8);
            float inv = 1.f / ss;
            preg[0][r] = e0 * inv;
            preg[1][r] = e1 * inv;
            preg[2][r] = e2 * inv;
            preg[3][r] = e3 * inv;
        }
    }
    __syncthreads();   // (3) all Q/K reads done -> safe to overlay P

    // ---- write P (plain f16) into dead Q/K regions (own-wave rows only) ----
    {
        _Float16* dsth = (h < 2) ? qh : kh;
        int pb = (h & 1) * 4096;
        #pragma unroll
        for (int ct = 0; ct < 4; ++ct) {
            #pragma unroll
            for (int r = 0; r < 4; ++r) {
                int row = rg * 16 + lg * 4 + r, col = ct * 16 + l15;
                dsth[pb + sw64p(row, col)] = (_Float16)preg[ct][r];
            }
        }
    }
    // no barrier: AV reads only this wave's P rows

    // ---- AV: O = P @ V (V hoisted); O -> xoh plain f16 ----
    {
        const _Float16* psh = (h < 2) ? qh : kh;
        int pb = (h & 1) * 4096;
        f16x8 vbh[2][2];
        #pragma unroll
        for (int ks = 0; ks < 2; ++ks)
            #pragma unroll
            for (int ct = 0; ct < 2; ++ct)
                vbh[ks][ct] = *(const f16x8*)&vth[sw64(qo + ct * 16 + l15, ks * 32 + lg * 8)];
        f32x4v om[2];
        om[0] = 0.0f; om[1] = 0.0f;
        #pragma unroll
        for (int ks = 0; ks < 2; ++ks) {
            f16x8 pah = *(const f16x8*)&psh[pb + sw64p(rg * 16 + l15, ks * 32 + lg * 8)];
            #pragma unroll
            for (int ct = 0; ct < 2; ++ct)
                om[ct] = MFMA16(pah, vbh[ks][ct], om[ct]);
        }
        #pragma unroll
        for (int ct = 0; ct < 2; ++ct) {
            #pragma unroll
            for (int r = 0; r < 4; ++r) {
                int row = rg * 16 + lg * 4 + r, col = qo + ct * 16 + l15;
                xoh[sw128(row, col)] = (_Float16)om[ct][r];
            }
        }
    }
    __syncthreads();   // (4)

    // ---- proj -> xf (attn-only; residual added at LN2 from registers) ----
    {
        int rt = w & 3, cb = (w >> 2) * 32;
        f32x4v pm[2], pc[2];
        pm[0] = 0.0f; pm[1] = 0.0f; pc[0] = 0.0f; pc[1] = 0.0f;
        #pragma unroll
        for (int ks = 0; ks < 4; ++ks) {
            f16x8 ah = *(const f16x8*)&xoh[sw128(rt * 16 + l15, ks * 32 + lg * 8)];
            #pragma unroll
            for (int ct = 0; ct < 2; ++ct) {
                int c = cb + ct * 16 + l15;
                f16x8 bh = *(const f16x8*)(wp_h + (size_t)c * DIM + ks * 32 + lg * 8);
                f16x8 bl = *(const f16x8*)(wp_l + (size_t)c * DIM + ks * 32 + lg * 8);
                pm[ct] = MFMA16(ah, bh, pm[ct]);
                pc[ct] = MFMA16(ah, bl, pc[ct]);
            }
        }
        #pragma unroll
        for (int ct = 0; ct < 2; ++ct) {
            int c = cb + ct * 16 + l15;
            float bp = b_proj[c];
            #pragma unroll
            for (int r = 0; r < 4; ++r) {
                int q = rt * 16 + lg * 4 + r;
                xf[q * XFS + c] = pm[ct][r] + pc[ct][r] * LO_INV + bp;
            }
        }
    }
    __syncthreads();   // (5)

    // ---- LN2: 16 threads per token; residual from xorig regs; publish m,rs;
    //      write full x2 back to xf for the gate ----
    float vrow[8];
    _Float16 yh[8];
    {
        int tt = tid >> 4, sub = tid & 15;
        float* xr = xf + tt * XFS + sub * 8;
        float s = 0.f, sq = 0.f;
        #pragma unroll
        for (int j = 0; j < 8; ++j) {
            float t = xorig[j] + xr[j];
            vrow[j] = t;
            s += t;
            sq = fmaf(t, t, sq);
        }
        s += __shfl_xor(s, 1); sq += __shfl_xor(sq, 1);
        s += __shfl_xor(s, 2); sq += __shfl_xor(sq, 2);
        s += __shfl_xor(s, 4); sq += __shfl_xor(sq, 4);
        s += __shfl_xor(s, 8); sq += __shfl_xor(sq, 8);
        float m = s * (1.f / DIM);
        float var = sq * (1.f / DIM) - m * m;
        float rs = rsqrtf(var + EPS);
        #pragma unroll
        for (int j = 0; j < 8; ++j) {
            int k = sub * 8 + j;
            yh[j] = (_Float16)((vrow[j] - m) * rs * ln2_g[k] + ln2_b[k]);
            xr[j] = vrow[j];   // publish full x2 row for the gate
        }
        if (sub == 0) { mrs[tt * 2] = m; mrs[tt * 2 + 1] = rs; }
    }
    __syncthreads();   // (6)

    // ---- gate (algebraic fold): thread -> (token tid&63, expert tid>>6) ----
    // expert index is wave-uniform -> scalar gw2/SA loads
    {
        int tk = tid & 63, eg = tid >> 6;
        const float* g0 = gw2 + eg * DIM;
        float S_e = SA[eg * 2], A_e = SA[eg * 2 + 1];
        float m = mrs[tk * 2], rs = mrs[tk * 2 + 1];
        const float* xr = xf + tk * XFS;
        float a0 = 0.f, a1 = 0.f, a2 = 0.f, a3 = 0.f;
        #pragma unroll 4
        for (int k = 0; k < DIM; k += 4) {
            a0 = fmaf(xr[k],     g0[k],     a0);
            a1 = fmaf(xr[k + 1], g0[k + 1], a1);
            a2 = fmaf(xr[k + 2], g0[k + 2], a2);
            a3 = fmaf(xr[k + 3], g0[k + 3], a3);
        }
        float dot = (a0 + a1) + (a2 + a3);
        lgs[tk * 20 + eg] = rs * (dot - m * S_e) + A_e;
    }
    __syncthreads();   // (7)

    // ---- routing + ballot rank + scatter (wave 0); other waves go to stores ----
    if (tid < 64) {
        float mx = -1e30f; int am = 0;
        #pragma unroll
        for (int e = 0; e < NEXP; ++e) {
            float v = lgs[tid * 20 + e];
            if (v > mx) { mx = v; am = e; }
        }
        float ss = 0.f;
        #pragma unroll
        for (int e = 0; e < NEXP; ++e) ss += expf(lgs[tid * 20 + e] - mx);
        float p = 1.f / ss;
        int gtok = tokbase + (tid >> 3) * 128 + (tid & 7);
        wgt[gtok] = p / (p + 1e-8f);

        int myrank = 0, mycnt = 0;
        #pragma unroll
        for (int e = 0; e < NEXP; ++e) {
            unsigned long long mask = __ballot(am == e);
            if (am == e) myrank = (int)__popcll(mask & ((1ull << tid) - 1));
            if (tid == e) mycnt = (int)__popcll(mask);
        }
        int bky = 0;
        if (tid < NEXP) bky = atomicAdd(&counts[tid * CPAD], mycnt);
        bky = __shfl(bky, am);
        perm[(size_t)am * T_TOK + bky + myrank] = gtok;
    }

    // ---- folded expert-weight cvt (256 threads; overlaps routing + stores) ----
    if (tid >= 64 && tid < 320) {
        int idx = wid * 256 + (tid - 64);   // 512 blocks * 256 = 131072 float4s
        float4 a = ((const float4*)w1)[idx];
        f16x4 h;
        h[0] = (_Float16)a.x; h[1] = (_Float16)a.y; h[2] = (_Float16)a.z; h[3] = (_Float16)a.w;
        *(f16x4*)(w1h + (size_t)idx * 4) = h;
        float4 b = ((const float4*)w2)[idx];
        f16x4 h2;
        h2[0] = (_Float16)b.x; h2[1] = (_Float16)b.y; h2[2] = (_Float16)b.z; h2[3] = (_Float16)b.w;
        *(f16x4*)(w2h + (size_t)idx * 4) = h2;
    }

    // ---- deferred global stores (all waves; drain overlaps endpgm) ----
    {
        int tt = tid >> 4, sub = tid & 15;
        int gtok = tokbase + (tt >> 3) * 128 + (tt & 7);
        float4* dst = (float4*)(x2 + (size_t)gtok * DIM + sub * 8);
        dst[0] = make_float4(vrow[0], vrow[1], vrow[2], vrow[3]);
        dst[1] = make_float4(vrow[4], vrow[5], vrow[6], vrow[7]);
        *(f16x8*)(y2 + (size_t)gtok * DIM + sub * 8) = *(const f16x8*)&yh[0];
    }
}

// ---------------- expert FFN (f16 MFMA, compacted grid) + weighted residual ----------------
__global__ __launch_bounds__(256, 3) void k_expert(
    const _Float16* __restrict__ y2, const float* __restrict__ x2,
    const _Float16* __restrict__ w1h, const float* __restrict__ b1,
    const _Float16* __restrict__ w2h, const float* __restrict__ b2,
    const int* __restrict__ perm, const int* __restrict__ counts,
    const float* __restrict__ wgt, float* __restrict__ out)
{
    __shared__ _Float16 yt[64 * 128];   // [tok][dim], sw128
    __shared__ _Float16 ht[64 * 256];   // [tok][hid], swht
    __shared__ int rows[64];

    int bflat = blockIdx.x;
    int e = -1, tile = 0, acc0 = 0;
    #pragma unroll
    for (int ee = 0; ee < NEXP; ++ee) {
        int t = (counts[ee * CPAD] + 63) >> 6;
        if (e < 0 && bflat < acc0 + t) { e = ee; tile = bflat - acc0; }
        acc0 += t;
    }
    if (e < 0) return;
    int cnt = counts[e * CPAD];
    int row0 = tile << 6;
    int nr = min(64, cnt - row0);
    int tid = threadIdx.x, wv = tid >> 6, lane = tid & 63;
    int l15 = lane & 15, lg = lane >> 4;

    if (tid < 64) rows[tid] = (tid < nr) ? perm[(size_t)e * T_TOK + row0 + tid] : 0;
    __syncthreads();
    f16x8 vz = (_Float16)0.0f;
    for (int i = tid; i < 1024; i += 256) {
        int tt = i >> 4, k = (i & 15) * 8;
        f16x8 val = vz;
        if (tt < nr) val = *(const f16x8*)(y2 + (size_t)rows[tt] * DIM + k);
        *(f16x8*)&yt[sw128(tt, k)] = val;
    }
    __syncthreads();

    // GEMM1 as H^T = W1 @ Y^T: A = w1 rows (global), B = yt rows (LDS, hoisted)
    {
        f16x8 yb[4][4];
        #pragma unroll
        for (int ct = 0; ct < 4; ++ct)
            #pragma unroll
            for (int ks = 0; ks < 4; ++ks)
                yb[ct][ks] = *(const f16x8*)&yt[sw128(ct * 16 + l15, ks * 32 + lg * 8)];
        #pragma unroll
        for (int rt = 0; rt < 4; ++rt) {
            int hid_row = wv * 64 + rt * 16 + l15;
            f16x8 a1[4];
            #pragma unroll
            for (int ks = 0; ks < 4; ++ks)
                a1[ks] = *(const f16x8*)(w1h + ((size_t)e * EHID + hid_row) * DIM + ks * 32 + lg * 8);
            f32x4v acc[4];
            #pragma unroll
            for (int ct = 0; ct < 4; ++ct) acc[ct] = 0.0f;
            #pragma unroll
            for (int ct = 0; ct < 4; ++ct)
                #pragma unroll
                for (int ks = 0; ks < 4; ++ks)
                    acc[ct] = MFMA16(a1[ks], yb[ct][ks], acc[ct]);
            int hid0 = wv * 64 + rt * 16 + lg * 4;
            float4 bb4 = *(const float4*)(b1 + e * EHID + hid0);
            float bbv[4] = {bb4.x, bb4.y, bb4.z, bb4.w};
            #pragma unroll
            for (int ct = 0; ct < 4; ++ct) {
                f16x4 hv;
                #pragma unroll
                for (int r = 0; r < 4; ++r) {
                    float a = acc[ct][r] + bbv[r];
                    float gl = 0.5f * a * (1.f + erff(a * 0.70710678118654752f));
                    hv[r] = (_Float16)gl;
                }
                int tok = ct * 16 + l15;
                *(f16x4*)&ht[swht(tok, hid0)] = hv;
            }
        }
    }
    __syncthreads();

    // GEMM2: out = H @ W2^T: A = ht rows (LDS), B = w2 rows (global, hoisted)
    {
        f16x8 wb[2][8];
        #pragma unroll
        for (int ct = 0; ct < 2; ++ct) {
            int c = wv * 32 + ct * 16 + l15;
            #pragma unroll
            for (int ks = 0; ks < 8; ++ks)
                wb[ct][ks] = *(const f16x8*)(w2h + ((size_t)e * DIM + c) * EHID + ks * 32 + lg * 8);
        }
        #pragma unroll
        for (int rt = 0; rt < 4; ++rt) {
            f16x8 af[8];
            #pragma unroll
            for (int ks = 0; ks < 8; ++ks)
                af[ks] = *(const f16x8*)&ht[swht(rt * 16 + l15, ks * 32 + lg * 8)];
            f32x4v acc2[2];
            acc2[0] = 0.0f; acc2[1] = 0.0f;
            #pragma unroll
            for (int ks = 0; ks < 8; ++ks)
                #pragma unroll
                for (int ct = 0; ct < 2; ++ct)
                    acc2[ct] = MFMA16(af[ks], wb[ct][ks], acc2[ct]);
            #pragma unroll
            for (int ct = 0; ct < 2; ++ct) {
                int c = wv * 32 + ct * 16 + l15;
                float bb = b2[e * DIM + c];
                #pragma unroll
                for (int r = 0; r < 4; ++r) {
                    int tt = rt * 16 + lg * 4 + r;
                    if (tt < nr) {
                        int gtok = rows[tt];
                        size_t go = (size_t)gtok * DIM + c;
                        out[go] = x2[go] + wgt[gtok] * (acc2[ct][r] + bb);
                    }
                }
            }
        }
    }
}

// ---------------- launch ----------------
extern "C" void kernel_launch(void* const* d_in, const int* in_sizes, int n_in,
                              void* d_out, int out_size, void* d_ws, size_t ws_size,
                              hipStream_t stream) {
    const float* x      = (const float*)d_in[0];
    const float* ln1_g  = (const float*)d_in[1];
    const float* ln1_b  = (const float*)d_in[2];
    const float* w_qkv  = (const float*)d_in[3];
    const float* b_qkv  = (const float*)d_in[4];
    const float* w_proj = (const float*)d_in[5];
    const float* b_proj = (const float*)d_in[6];
    const float* ln2_g  = (const float*)d_in[7];
    const float* ln2_b  = (const float*)d_in[8];
    const float* gate_w = (const float*)d_in[9];
    const float* w1     = (const float*)d_in[10];
    const float* b1     = (const float*)d_in[11];
    const float* w2     = (const float*)d_in[12];
    const float* b2     = (const float*)d_in[13];
    float* out = (float*)d_out;

    char* p = (char*)d_ws;
    float* x2 = (float*)p;                 p += (size_t)T_TOK * DIM * 4;
    _Float16* y2 = (_Float16*)p;           p += (size_t)T_TOK * DIM * 2;
    _Float16* wq_h = (_Float16*)p;         p += 3 * DIM * DIM * 2;
    _Float16* wp_h = (_Float16*)p;         p += DIM * DIM * 2;
    _Float16* wp_l = (_Float16*)p;         p += DIM * DIM * 2;
    _Float16* w1h = (_Float16*)p;          p += NEXP * EHID * DIM * 2;
    _Float16* w2h = (_Float16*)p;          p += NEXP * EHID * DIM * 2;
    float* gw2 = (float*)p;                p += NEXP * DIM * 4;
    float* SA = (float*)p;                 p += 2 * NEXP * 4;
    float* wgt = (float*)p;                p += T_TOK * 4;
    int* perm = (int*)p;                   p += (size_t)NEXP * T_TOK * 4;
    int* counts = (int*)p;                 p += NEXP * CPAD * 4;

    k_cvt<<<48, 256, 0, stream>>>(w_qkv, w_proj, gate_w, ln2_g, ln2_b,
                                  wq_h, wp_h, wp_l, gw2, SA, counts);
    k_attn<<<NWIN, 1024, 0, stream>>>(x, ln1_g, ln1_b, wq_h, b_qkv,
                                      wp_h, wp_l, b_proj, ln2_g, ln2_b, gw2, SA,
                                      w1, w2, w1h, w2h,
                                      x2, y2, wgt, perm, counts);
    k_expert<<<544, 256, 0, stream>>>(y2, x2, w1h, b1, w2h, b2, perm, counts, wgt, out);
}

// Round 24
// 95.862 us; speedup vs baseline: 1.0159x; 1.0159x over previous
//
#include <hip/hip_runtime.h>
#include <math.h>

#define T_TOK 32768      // B*N = 2*16384
#define DIM 128
#define NHEADS 4
#define HD 32
#define NEXP 16
#define EHID 256
#define NWIN 512
#define EPS 1e-5f
#define CPAD 16          // counter padding: 64B apart
#define XFS 133          // xf stride (133%32=5 -> 2-way max on fp32 accesses)

typedef _Float16 f16x8 __attribute__((ext_vector_type(8)));
typedef _Float16 f16x4 __attribute__((ext_vector_type(4)));
typedef float f32x4v __attribute__((ext_vector_type(4)));

#define MFMA16(a, b, c) __builtin_amdgcn_mfma_f32_16x16x32_f16(a, b, c, 0, 0, 0)
#define LO_SCALE 4096.0f
#define LO_INV (1.0f / 4096.0f)

// swizzled f16 index into a [R][128] tile (16B chunks XOR'd by row&7)
__device__ __forceinline__ int sw128(int r, int c) {
    return r * 128 + (((c >> 3) ^ (r & 7)) << 3) + (c & 7);
}
// swizzled f16 index into a [R][64] tile (V^T)
__device__ __forceinline__ int sw64(int r, int c) {
    return r * 64 + (((c >> 3) ^ (r & 7)) << 3) + (c & 7);
}
// P-tile swizzle: XOR = (row ^ row>>3)&7
__device__ __forceinline__ int sw64p(int r, int c) {
    return r * 64 + (((c >> 3) ^ ((r ^ (r >> 3)) & 7)) << 3) + (c & 7);
}
// swizzled f16 index into [64 tok][256 hid] tile
__device__ __forceinline__ int swht(int tok, int hid) {
    return tok * 256 + (((hid >> 3) ^ (tok & 7)) << 3) + (hid & 7);
}

// ---------------- qkv(hi)/proj(hi+lo) conversion + gate fold + counter zero ----------------
__global__ __launch_bounds__(256) void k_cvt(
    const float* __restrict__ wqkv, const float* __restrict__ wproj,
    const float* __restrict__ gw, const float* __restrict__ ln2_g,
    const float* __restrict__ ln2_b,
    _Float16* __restrict__ wq_h,
    _Float16* __restrict__ wp_h, _Float16* __restrict__ wp_l,
    float* __restrict__ gw2, float* __restrict__ SA,
    int* __restrict__ counts)
{
    int i = blockIdx.x * 256 + threadIdx.x;
    if (blockIdx.x == 0 && threadIdx.x < NEXP * CPAD) counts[threadIdx.x] = 0;
    if (i < 3 * DIM * DIM / 4) {
        float4 f = ((const float4*)wqkv)[i];
        f16x4 h;
        h[0] = (_Float16)f.x; h[1] = (_Float16)f.y; h[2] = (_Float16)f.z; h[3] = (_Float16)f.w;
        *(f16x4*)(wq_h + (size_t)i * 4) = h;
    }
    if (i < DIM * DIM / 4) {
        float4 f = ((const float4*)wproj)[i];
        float fv[4] = {f.x, f.y, f.z, f.w};
        f16x4 h, l;
        #pragma unroll
        for (int j = 0; j < 4; ++j) {
            _Float16 hh = (_Float16)fv[j];
            h[j] = hh;
            l[j] = (_Float16)((fv[j] - (float)hh) * LO_SCALE);
        }
        *(f16x4*)(wp_h + (size_t)i * 4) = h;
        *(f16x4*)(wp_l + (size_t)i * 4) = l;
    }
    if (i < NEXP * DIM) {
        int k = i & 127;
        gw2[i] = ln2_g[k] * gw[i];
    }
    if (blockIdx.x == 1 && threadIdx.x < 2 * NEXP) {
        int e = threadIdx.x >> 1;
        const float* gr = gw + e * DIM;
        float s = 0.f;
        if (threadIdx.x & 1) {
            for (int k = 0; k < DIM; ++k) s = fmaf(ln2_b[k], gr[k], s);
        } else {
            for (int k = 0; k < DIM; ++k) s = fmaf(ln2_g[k], gr[k], s);
        }
        SA[threadIdx.x] = s;   // SA[2e]=S_e, SA[2e+1]=A_e
    }
}

// ---------------- fused LN1 + attn + proj + residual + LN2 + gate + routing ----------------
// 1024 threads (16 waves), 64KB LDS. Plain-f16 activations; split-fp16 proj
// weights only. NOTE: no min-occupancy arg in launch_bounds (spills otherwise).
__global__ __launch_bounds__(1024) void k_attn(
    const float* __restrict__ x,
    const float* __restrict__ ln_g, const float* __restrict__ ln_b,
    const _Float16* __restrict__ wq_h, const float* __restrict__ b_qkv,
    const _Float16* __restrict__ wp_h, const _Float16* __restrict__ wp_l,
    const float* __restrict__ b_proj,
    const float* __restrict__ ln2_g, const float* __restrict__ ln2_b,
    const float* __restrict__ gw2, const float* __restrict__ SA,
    const float* __restrict__ w1, const float* __restrict__ w2,
    _Float16* __restrict__ w1h, _Float16* __restrict__ w2h,
    float* __restrict__ x2, _Float16* __restrict__ y2,
    float* __restrict__ wgt, int* __restrict__ perm, int* __restrict__ counts)
{
    __shared__ __align__(16) char smem[65536];
    _Float16* xoh = (_Float16*)(smem);            // LN out; later O (plain f16)
    _Float16* qh  = (_Float16*)(smem + 16384);    // Q; later P(h0),P(h1)
    _Float16* kh  = (_Float16*)(smem + 32768);    // K; later P(h2),P(h3)
    _Float16* vth = (_Float16*)(smem + 49152);    // V^T [d][tok]
    // post-proj aliases (qh/kh/vth dead after barrier 4)
    float* xf  = (float*)(smem + 16384);          // [64][133] fp32 (ends 50432)
    float* mrs = (float*)(smem + 50688);          // [64][2] m,rs
    float* lgs = (float*)(smem + 51712);          // [64][20] gate logits (ends 56832)

    int tid = threadIdx.x;
    int w = tid >> 6, lane = tid & 63;
    int l15 = lane & 15, lg = lane >> 4;
    int wid = blockIdx.x;
    int wb = wid >> 8, wrr = (wid >> 4) & 15, wcc = wid & 15;
    const int tokbase = wb * 16384 + wrr * 1024 + wcc * 8;
    const size_t base = (size_t)tokbase * DIM;

    // ---- prefetch QKV B-frags (hi only) + bias + proj x-residual ----
    // wave w owns tile w; waves 0-7 also own tile 16+w  (24 tiles of 16 cols)
    f16x8 qbh[2][4];
    float qbias[2];
    #pragma unroll
    for (int tl = 0; tl < 2; ++tl) {
        if (tl == 1 && w >= 8) break;
        int o = ((tl == 0) ? w : 16 + w) * 16 + l15;
        qbias[tl] = b_qkv[o];
        #pragma unroll
        for (int ks = 0; ks < 4; ++ks)
            qbh[tl][ks] = *(const f16x8*)(wq_h + (size_t)o * DIM + ks * 32 + lg * 8);
    }
    float xres[8];
    {
        int rt = w & 3, cb = (w >> 2) * 32;
        #pragma unroll
        for (int ct = 0; ct < 2; ++ct) {
            int c = cb + ct * 16 + l15;
            #pragma unroll
            for (int r = 0; r < 4; ++r) {
                int q = rt * 16 + lg * 4 + r;
                xres[ct * 4 + r] = x[base + (size_t)(q >> 3) * 16384 + (size_t)(q & 7) * DIM + c];
            }
        }
    }

    // ---- LN1: 16 threads per token, 8 dims each; plain f16 out ----
    {
        int tt = tid >> 4, sub = tid & 15;
        const float* xr = x + base + (size_t)(tt >> 3) * 16384 + (size_t)(tt & 7) * DIM + sub * 8;
        float v[8];
        float s = 0.f, sq = 0.f;
        #pragma unroll
        for (int j = 0; j < 2; ++j) {
            float4 t4 = *(const float4*)(xr + j * 4);
            v[4 * j] = t4.x; v[4 * j + 1] = t4.y; v[4 * j + 2] = t4.z; v[4 * j + 3] = t4.w;
            s += (t4.x + t4.y) + (t4.z + t4.w);
            sq = fmaf(t4.x, t4.x, fmaf(t4.y, t4.y, fmaf(t4.z, t4.z, fmaf(t4.w, t4.w, sq))));
        }
        s += __shfl_xor(s, 1); sq += __shfl_xor(sq, 1);
        s += __shfl_xor(s, 2); sq += __shfl_xor(sq, 2);
        s += __shfl_xor(s, 4); sq += __shfl_xor(sq, 4);
        s += __shfl_xor(s, 8); sq += __shfl_xor(sq, 8);
        float m = s * (1.f / DIM);
        float var = sq * (1.f / DIM) - m * m;
        float rs = rsqrtf(var + EPS);
        _Float16 hh[8];
        #pragma unroll
        for (int j = 0; j < 8; ++j) {
            int k = sub * 8 + j;
            hh[j] = (_Float16)((v[j] - m) * rs * ln_g[k] + ln_b[k]);
        }
        *(f16x8*)&xoh[sw128(tt, sub * 8)] = *(const f16x8*)&hh[0];
    }
    __syncthreads();   // (1)

    // ---- QKV GEMM: <=2 col-tiles per wave, plain f16, 4 acc chains ----
    #pragma unroll
    for (int tl = 0; tl < 2; ++tl) {
        if (tl == 1 && w >= 8) break;
        int o = ((tl == 0) ? w : 16 + w) * 16 + l15;
        f32x4v am[4];
        #pragma unroll
        for (int rt = 0; rt < 4; ++rt) am[rt] = 0.0f;
        #pragma unroll
        for (int rt = 0; rt < 4; ++rt) {
            #pragma unroll
            for (int ks = 0; ks < 4; ++ks) {
                f16x8 ah = *(const f16x8*)&xoh[sw128(rt * 16 + l15, ks * 32 + lg * 8)];
                am[rt] = MFMA16(ah, qbh[tl][ks], am[rt]);
            }
        }
        float bias = qbias[tl];
        if (o < 256) {
            #pragma unroll
            for (int rt = 0; rt < 4; ++rt) {
                #pragma unroll
                for (int r = 0; r < 4; ++r) {
                    int row = rt * 16 + lg * 4 + r;
                    _Float16 h = (_Float16)(am[rt][r] + bias);
                    if (o < 128) qh[sw128(row, o)] = h;
                    else         kh[sw128(row, o - 128)] = h;
                }
            }
        } else {
            int d = o - 256;
            #pragma unroll
            for (int rt = 0; rt < 4; ++rt) {
                f16x4 vh4;
                #pragma unroll
                for (int r = 0; r < 4; ++r)
                    vh4[r] = (_Float16)(am[rt][r] + bias);
                *(f16x4*)&vth[sw64(d, rt * 16 + lg * 4)] = vh4;
            }
        }
    }
    __syncthreads();   // (2)

    // ---- scores + softmax: wave w -> head w&3, row-group w>>2 ----
    const float scale = 0.17677669529663687f;  // 1/sqrt(32)
    int h = w & 3;
    int qo = h * HD, rg = w >> 2;
    float preg[4][4];
    {
        f16x8 kbh[4];
        #pragma unroll
        for (int ct = 0; ct < 4; ++ct)
            kbh[ct] = *(const f16x8*)&kh[sw128(ct * 16 + l15, qo + lg * 8)];
        f16x8 qah = *(const f16x8*)&qh[sw128(rg * 16 + l15, qo + lg * 8)];
        f32x4v sm[4];
        #pragma unroll
        for (int ct = 0; ct < 4; ++ct) {
            sm[ct] = 0.0f;
            sm[ct] = MFMA16(qah, kbh[ct], sm[ct]);
        }
        #pragma unroll
        for (int r = 0; r < 4; ++r) {
            float v0 = sm[0][r] * scale;
            float v1 = sm[1][r] * scale;
            float v2 = sm[2][r] * scale;
            float v3 = sm[3][r] * scale;
            float mx = fmaxf(fmaxf(v0, v1), fmaxf(v2, v3));
            mx = fmaxf(mx, __shfl_xor(mx, 1));
            mx = fmaxf(mx, __shfl_xor(mx, 2));
            mx = fmaxf(mx, __shfl_xor(mx, 4));
            mx = fmaxf(mx, __shfl_xor(mx, 8));
            float e0 = expf(v0 - mx), e1 = expf(v1 - mx), e2 = expf(v2 - mx), e3 = expf(v3 - mx);
            float ss = (e0 + e1) + (e2 + e3);
            ss += __shfl_xor(ss, 1); ss += __shfl_xor(ss, 2);
            ss += __shfl_xor(ss, 4); ss += __shfl_xor(ss, 8);
            float inv = 1.f / ss;
            preg[0][r] = e0 * inv;
            preg[1][r] = e1 * inv;
            preg[2][r] = e2 * inv;
            preg[3][r] = e3 * inv;
        }
    }
    __syncthreads();   // (3) all Q/K reads done -> safe to overlay P

    // ---- write P (plain f16) into dead Q/K regions (own-wave rows only) ----
    {
        _Float16* dsth = (h < 2) ? qh : kh;
        int pb = (h & 1) * 4096;
        #pragma unroll
        for (int ct = 0; ct < 4; ++ct) {
            #pragma unroll
            for (int r = 0; r < 4; ++r) {
                int row = rg * 16 + lg * 4 + r, col = ct * 16 + l15;
                dsth[pb + sw64p(row, col)] = (_Float16)preg[ct][r];
            }
        }
    }
    // no barrier: AV reads only this wave's P rows

    // ---- AV: O = P @ V (V hoisted); O -> xoh plain f16 ----
    {
        const _Float16* psh = (h < 2) ? qh : kh;
        int pb = (h & 1) * 4096;
        f16x8 vbh[2][2];
        #pragma unroll
        for (int ks = 0; ks < 2; ++ks)
            #pragma unroll
            for (int ct = 0; ct < 2; ++ct)
                vbh[ks][ct] = *(const f16x8*)&vth[sw64(qo + ct * 16 + l15, ks * 32 + lg * 8)];
        f32x4v om[2];
        om[0] = 0.0f; om[1] = 0.0f;
        #pragma unroll
        for (int ks = 0; ks < 2; ++ks) {
            f16x8 pah = *(const f16x8*)&psh[pb + sw64p(rg * 16 + l15, ks * 32 + lg * 8)];
            #pragma unroll
            for (int ct = 0; ct < 2; ++ct)
                om[ct] = MFMA16(pah, vbh[ks][ct], om[ct]);
        }
        #pragma unroll
        for (int ct = 0; ct < 2; ++ct) {
            #pragma unroll
            for (int r = 0; r < 4; ++r) {
                int row = rg * 16 + lg * 4 + r, col = qo + ct * 16 + l15;
                xoh[sw128(row, col)] = (_Float16)om[ct][r];
            }
        }
    }
    __syncthreads();   // (4)

    // ---- proj + residual -> xf (split WEIGHTS: 2-term; inline B loads) ----
    {
        int rt = w & 3, cb = (w >> 2) * 32;
        f32x4v pm[2], pc[2];
        pm[0] = 0.0f; pm[1] = 0.0f; pc[0] = 0.0f; pc[1] = 0.0f;
        #pragma unroll
        for (int ks = 0; ks < 4; ++ks) {
            f16x8 ah = *(const f16x8*)&xoh[sw128(rt * 16 + l15, ks * 32 + lg * 8)];
            #pragma unroll
            for (int ct = 0; ct < 2; ++ct) {
                int c = cb + ct * 16 + l15;
                f16x8 bh = *(const f16x8*)(wp_h + (size_t)c * DIM + ks * 32 + lg * 8);
                f16x8 bl = *(const f16x8*)(wp_l + (size_t)c * DIM + ks * 32 + lg * 8);
                pm[ct] = MFMA16(ah, bh, pm[ct]);
                pc[ct] = MFMA16(ah, bl, pc[ct]);
            }
        }
        #pragma unroll
        for (int ct = 0; ct < 2; ++ct) {
            int c = cb + ct * 16 + l15;
            float bp = b_proj[c];
            #pragma unroll
            for (int r = 0; r < 4; ++r) {
                int q = rt * 16 + lg * 4 + r;
                xf[q * XFS + c] = xres[ct * 4 + r] + (pm[ct][r] + pc[ct][r] * LO_INV + bp);
            }
        }
    }
    __syncthreads();   // (5)

    // ---- LN2: 16 threads per token; y kept in regs; publish m,rs ----
    float vrow[8];
    _Float16 yh[8];
    {
        int tt = tid >> 4, sub = tid & 15;
        const float* xr = xf + tt * XFS + sub * 8;
        float s = 0.f, sq = 0.f;
        #pragma unroll
        for (int j = 0; j < 8; ++j) {
            float t = xr[j];
            vrow[j] = t;
            s += t;
            sq = fmaf(t, t, sq);
        }
        s += __shfl_xor(s, 1); sq += __shfl_xor(sq, 1);
        s += __shfl_xor(s, 2); sq += __shfl_xor(sq, 2);
        s += __shfl_xor(s, 4); sq += __shfl_xor(sq, 4);
        s += __shfl_xor(s, 8); sq += __shfl_xor(sq, 8);
        float m = s * (1.f / DIM);
        float var = sq * (1.f / DIM) - m * m;
        float rs = rsqrtf(var + EPS);
        #pragma unroll
        for (int j = 0; j < 8; ++j) {
            int k = sub * 8 + j;
            yh[j] = (_Float16)((vrow[j] - m) * rs * ln2_g[k] + ln2_b[k]);
        }
        if (sub == 0) { mrs[tt * 2] = m; mrs[tt * 2 + 1] = rs; }
    }
    __syncthreads();   // (6)

    // ---- gate (algebraic fold): thread -> (token tid&63, expert tid>>6) ----
    // expert index is wave-uniform -> scalar gw2/SA loads
    {
        int tk = tid & 63, eg = tid >> 6;
        const float* g0 = gw2 + eg * DIM;
        float S_e = SA[eg * 2], A_e = SA[eg * 2 + 1];
        float m = mrs[tk * 2], rs = mrs[tk * 2 + 1];
        const float* xr = xf + tk * XFS;
        float a0 = 0.f, a1 = 0.f, a2 = 0.f, a3 = 0.f;
        #pragma unroll 4
        for (int k = 0; k < DIM; k += 4) {
            a0 = fmaf(xr[k],     g0[k],     a0);
            a1 = fmaf(xr[k + 1], g0[k + 1], a1);
            a2 = fmaf(xr[k + 2], g0[k + 2], a2);
            a3 = fmaf(xr[k + 3], g0[k + 3], a3);
        }
        float dot = (a0 + a1) + (a2 + a3);
        lgs[tk * 20 + eg] = rs * (dot - m * S_e) + A_e;
    }
    __syncthreads();   // (7)

    // ---- routing + ballot rank + scatter (wave 0); other waves go to stores ----
    if (tid < 64) {
        float mx = -1e30f; int am = 0;
        #pragma unroll
        for (int e = 0; e < NEXP; ++e) {
            float v = lgs[tid * 20 + e];
            if (v > mx) { mx = v; am = e; }
        }
        float ss = 0.f;
        #pragma unroll
        for (int e = 0; e < NEXP; ++e) ss += expf(lgs[tid * 20 + e] - mx);
        float p = 1.f / ss;
        int gtok = tokbase + (tid >> 3) * 128 + (tid & 7);
        wgt[gtok] = p / (p + 1e-8f);

        int myrank = 0, mycnt = 0;
        #pragma unroll
        for (int e = 0; e < NEXP; ++e) {
            unsigned long long mask = __ballot(am == e);
            if (am == e) myrank = (int)__popcll(mask & ((1ull << tid) - 1));
            if (tid == e) mycnt = (int)__popcll(mask);
        }
        int bky = 0;
        if (tid < NEXP) bky = atomicAdd(&counts[tid * CPAD], mycnt);
        bky = __shfl(bky, am);
        perm[(size_t)am * T_TOK + bky + myrank] = gtok;
    }

    // ---- folded expert-weight cvt (256 threads; overlaps routing + stores) ----
    if (tid >= 64 && tid < 320) {
        int idx = wid * 256 + (tid - 64);   // 512 blocks * 256 = 131072 float4s
        float4 a = ((const float4*)w1)[idx];
        f16x4 h;
        h[0] = (_Float16)a.x; h[1] = (_Float16)a.y; h[2] = (_Float16)a.z; h[3] = (_Float16)a.w;
        *(f16x4*)(w1h + (size_t)idx * 4) = h;
        float4 b = ((const float4*)w2)[idx];
        f16x4 h2;
        h2[0] = (_Float16)b.x; h2[1] = (_Float16)b.y; h2[2] = (_Float16)b.z; h2[3] = (_Float16)b.w;
        *(f16x4*)(w2h + (size_t)idx * 4) = h2;
    }

    // ---- deferred global stores (all waves; drain overlaps endpgm) ----
    {
        int tt = tid >> 4, sub = tid & 15;
        int gtok = tokbase + (tt >> 3) * 128 + (tt & 7);
        float4* dst = (float4*)(x2 + (size_t)gtok * DIM + sub * 8);
        dst[0] = make_float4(vrow[0], vrow[1], vrow[2], vrow[3]);
        dst[1] = make_float4(vrow[4], vrow[5], vrow[6], vrow[7]);
        *(f16x8*)(y2 + (size_t)gtok * DIM + sub * 8) = *(const f16x8*)&yh[0];
    }
}

// ---------------- expert FFN (f16 MFMA, compacted grid) + weighted residual ----------------
__global__ __launch_bounds__(256, 3) void k_expert(
    const _Float16* __restrict__ y2, const float* __restrict__ x2,
    const _Float16* __restrict__ w1h, const float* __restrict__ b1,
    const _Float16* __restrict__ w2h, const float* __restrict__ b2,
    const int* __restrict__ perm, const int* __restrict__ counts,
    const float* __restrict__ wgt, float* __restrict__ out)
{
    __shared__ _Float16 yt[64 * 128];   // [tok][dim], sw128
    __shared__ _Float16 ht[64 * 256];   // [tok][hid], swht
    __shared__ int rows[64];

    int bflat = blockIdx.x;
    int e = -1, tile = 0, acc0 = 0;
    #pragma unroll
    for (int ee = 0; ee < NEXP; ++ee) {
        int t = (counts[ee * CPAD] + 63) >> 6;
        if (e < 0 && bflat < acc0 + t) { e = ee; tile = bflat - acc0; }
        acc0 += t;
    }
    if (e < 0) return;
    int cnt = counts[e * CPAD];
    int row0 = tile << 6;
    int nr = min(64, cnt - row0);
    int tid = threadIdx.x, wv = tid >> 6, lane = tid & 63;
    int l15 = lane & 15, lg = lane >> 4;

    if (tid < 64) rows[tid] = (tid < nr) ? perm[(size_t)e * T_TOK + row0 + tid] : 0;
    __syncthreads();
    f16x8 vz = (_Float16)0.0f;
    for (int i = tid; i < 1024; i += 256) {
        int tt = i >> 4, k = (i & 15) * 8;
        f16x8 val = vz;
        if (tt < nr) val = *(const f16x8*)(y2 + (size_t)rows[tt] * DIM + k);
        *(f16x8*)&yt[sw128(tt, k)] = val;
    }
    __syncthreads();

    // GEMM1 as H^T = W1 @ Y^T: A = w1 rows (global), B = yt rows (LDS, hoisted)
    {
        f16x8 yb[4][4];
        #pragma unroll
        for (int ct = 0; ct < 4; ++ct)
            #pragma unroll
            for (int ks = 0; ks < 4; ++ks)
                yb[ct][ks] = *(const f16x8*)&yt[sw128(ct * 16 + l15, ks * 32 + lg * 8)];
        #pragma unroll
        for (int rt = 0; rt < 4; ++rt) {
            int hid_row = wv * 64 + rt * 16 + l15;
            f16x8 a1[4];
            #pragma unroll
            for (int ks = 0; ks < 4; ++ks)
                a1[ks] = *(const f16x8*)(w1h + ((size_t)e * EHID + hid_row) * DIM + ks * 32 + lg * 8);
            f32x4v acc[4];
            #pragma unroll
            for (int ct = 0; ct < 4; ++ct) acc[ct] = 0.0f;
            #pragma unroll
            for (int ct = 0; ct < 4; ++ct)
                #pragma unroll
                for (int ks = 0; ks < 4; ++ks)
                    acc[ct] = MFMA16(a1[ks], yb[ct][ks], acc[ct]);
            int hid0 = wv * 64 + rt * 16 + lg * 4;
            float4 bb4 = *(const float4*)(b1 + e * EHID + hid0);
            float bbv[4] = {bb4.x, bb4.y, bb4.z, bb4.w};
            #pragma unroll
            for (int ct = 0; ct < 4; ++ct) {
                f16x4 hv;
                #pragma unroll
                for (int r = 0; r < 4; ++r) {
                    float a = acc[ct][r] + bbv[r];
                    float gl = 0.5f * a * (1.f + erff(a * 0.70710678118654752f));
                    hv[r] = (_Float16)gl;
                }
                int tok = ct * 16 + l15;
                *(f16x4*)&ht[swht(tok, hid0)] = hv;
            }
        }
    }
    __syncthreads();

    // GEMM2: out = H @ W2^T: A = ht rows (LDS), B = w2 rows (global, hoisted)
    {
        f16x8 wb[2][8];
        #pragma unroll
        for (int ct = 0; ct < 2; ++ct) {
            int c = wv * 32 + ct * 16 + l15;
            #pragma unroll
            for (int ks = 0; ks < 8; ++ks)
                wb[ct][ks] = *(const f16x8*)(w2h + ((size_t)e * DIM + c) * EHID + ks * 32 + lg * 8);
        }
        #pragma unroll
        for (int rt = 0; rt < 4; ++rt) {
            f16x8 af[8];
            #pragma unroll
            for (int ks = 0; ks < 8; ++ks)
                af[ks] = *(const f16x8*)&ht[swht(rt * 16 + l15, ks * 32 + lg * 8)];
            f32x4v acc2[2];
            acc2[0] = 0.0f; acc2[1] = 0.0f;
            #pragma unroll
            for (int ks = 0; ks < 8; ++ks)
                #pragma unroll
                for (int ct = 0; ct < 2; ++ct)
                    acc2[ct] = MFMA16(af[ks], wb[ct][ks], acc2[ct]);
            #pragma unroll
            for (int ct = 0; ct < 2; ++ct) {
                int c = wv * 32 + ct * 16 + l15;
                float bb = b2[e * DIM + c];
                #pragma unroll
                for (int r = 0; r < 4; ++r) {
                    int tt = rt * 16 + lg * 4 + r;
                    if (tt < nr) {
                        int gtok = rows[tt];
                        size_t go = (size_t)gtok * DIM + c;
                        out[go] = x2[go] + wgt[gtok] * (acc2[ct][r] + bb);
                    }
                }
            }
        }
    }
}

// ---------------- launch ----------------
extern "C" void kernel_launch(void* const* d_in, const int* in_sizes, int n_in,
                              void* d_out, int out_size, void* d_ws, size_t ws_size,
                              hipStream_t stream) {
    const float* x      = (const float*)d_in[0];
    const float* ln1_g  = (const float*)d_in[1];
    const float* ln1_b  = (const float*)d_in[2];
    const float* w_qkv  = (const float*)d_in[3];
    const float* b_qkv  = (const float*)d_in[4];
    const float* w_proj = (const float*)d_in[5];
    const float* b_proj = (const float*)d_in[6];
    const float* ln2_g  = (const float*)d_in[7];
    const float* ln2_b  = (const float*)d_in[8];
    const float* gate_w = (const float*)d_in[9];
    const float* w1     = (const float*)d_in[10];
    const float* b1     = (const float*)d_in[11];
    const float* w2     = (const float*)d_in[12];
    const float* b2     = (const float*)d_in[13];
    float* out = (float*)d_out;

    char* p = (char*)d_ws;
    float* x2 = (float*)p;                 p += (size_t)T_TOK * DIM * 4;
    _Float16* y2 = (_Float16*)p;           p += (size_t)T_TOK * DIM * 2;
    _Float16* wq_h = (_Float16*)p;         p += 3 * DIM * DIM * 2;
    _Float16* wp_h = (_Float16*)p;         p += DIM * DIM * 2;
    _Float16* wp_l = (_Float16*)p;         p += DIM * DIM * 2;
    _Float16* w1h = (_Float16*)p;          p += NEXP * EHID * DIM * 2;
    _Float16* w2h = (_Float16*)p;          p += NEXP * EHID * DIM * 2;
    float* gw2 = (float*)p;                p += NEXP * DIM * 4;
    float* SA = (float*)p;                 p += 2 * NEXP * 4;
    float* wgt = (float*)p;                p += T_TOK * 4;
    int* perm = (int*)p;                   p += (size_t)NEXP * T_TOK * 4;
    int* counts = (int*)p;                 p += NEXP * CPAD * 4;

    k_cvt<<<48, 256, 0, stream>>>(w_qkv, w_proj, gate_w, ln2_g, ln2_b,
                                  wq_h, wp_h, wp_l, gw2, SA, counts);
    k_attn<<<NWIN, 1024, 0, stream>>>(x, ln1_g, ln1_b, wq_h, b_qkv,
                                      wp_h, wp_l, b_proj, ln2_g, ln2_b, gw2, SA,
                                      w1, w2, w1h, w2h,
                                      x2, y2, wgt, perm, counts);
    k_expert<<<544, 256, 0, stream>>>(y2, x2, w1h, b1, w2h, b2, perm, counts, wgt, out);
}